// Round 1
// 133.454 us; speedup vs baseline: 1.0178x; 1.0178x over previous
//
#include <hip/hip_runtime.h>
#include <hip/hip_bf16.h>

typedef unsigned short ushort_t;
typedef __attribute__((ext_vector_type(8))) short short8;   // 8 bf16 (4 VGPRs)
typedef __attribute__((ext_vector_type(4))) short short4v;  // 4 bf16 (2 VGPRs)
typedef __attribute__((ext_vector_type(4))) float f32x4;    // 4 fp32 acc

__device__ __forceinline__ float bf2f(ushort_t u) {
    unsigned int x = ((unsigned int)u) << 16;
    float f; __builtin_memcpy(&f, &x, 4); return f;
}
// RNE bf16 via the HIP cast — lowers to hardware cvt (fuses to v_cvt_pk_bf16_f32
// for pairs), numerically identical to the old bit-trick RNE.
__device__ __forceinline__ ushort_t f2bf(float f) {
    __hip_bfloat16 h = __float2bfloat16(f);
    ushort_t u; __builtin_memcpy(&u, &h, 2); return u;
}
__device__ __forceinline__ unsigned packbf2(float a, float b) {
    return (unsigned)f2bf(a) | ((unsigned)f2bf(b) << 16);
}

constexpr int E  = 1024;
constexpr int Hd = 64;
constexpr int S  = 2048;
constexpr int ROWS = 8 * 2048;   // 16384
constexpr int NTOT = 192;
constexpr int LST  = 88;         // LDS row stride (2-way max on reads/writes)

// ---------------------------------------------------------------------------
// prep: WT[192][1024] bf16, rows 0-63 = Wq^T, 64-127 = Wk^T, 128-191 = Wv^T
__global__ __launch_bounds__(256)
void prep_wt(const float* __restrict__ Wk, const float* __restrict__ Wq,
             const float* __restrict__ Wv, ushort_t* __restrict__ WT)
{
    int idx = blockIdx.x * 256 + threadIdx.x;
    int n = idx >> 10;
    int kk = idx & 1023;
    const float* W = (n < 64) ? Wq : ((n < 128) ? Wk : Wv);
    int h = n & 63;
    WT[idx] = f2bf(W[kk * Hd + h]);
}

// ---------------------------------------------------------------------------
// Projection v8: same structure as v7; XS staging now packs bf16 pairs via
// hardware cvt (4 packed converts instead of 8 bit-trick conversions).
__global__ __launch_bounds__(256)
void proj_v7(const float* __restrict__ x, const ushort_t* __restrict__ WT,
             ushort_t* __restrict__ qo, ushort_t* __restrict__ ko,
             ushort_t* __restrict__ vTo)
{
    __shared__ alignas(16) ushort_t XS[32][LST];

    const int t    = threadIdx.x;
    const int w    = t >> 6;
    const int lane = t & 63;
    const int m    = lane & 15;
    const int g    = lane >> 4;
    const int rb   = blockIdx.x * 32;

    f32x4 accq[2], acck[2], accv[2];
    #pragma unroll
    for (int j = 0; j < 2; ++j) {
        accq[j] = (f32x4){0.f, 0.f, 0.f, 0.f};
        acck[j] = (f32x4){0.f, 0.f, 0.f, 0.f};
        accv[j] = (f32x4){0.f, 0.f, 0.f, 0.f};
    }

    const float* xptr = x + (size_t)(rb + (t >> 3)) * E + (t & 7) * 8;
    const ushort_t* wqp = WT + (size_t)(w * 16 + m) * E + g * 8;
    const ushort_t* wkp = wqp + (size_t)64 * E;
    const ushort_t* wvp = wqp + (size_t)128 * E;

    float4 xp0, xp1;
    short8 pbq[2], pbk[2], pbv[2], cbq[2], cbk[2], cbv[2];

    xp0 = *(const float4*)xptr;
    xp1 = *(const float4*)(xptr + 4);
    #pragma unroll
    for (int kt = 0; kt < 2; ++kt) {
        pbq[kt] = *(const short8*)(wqp + kt * 32);
        pbk[kt] = *(const short8*)(wkp + kt * 32);
        pbv[kt] = *(const short8*)(wvp + kt * 32);
    }

    #pragma unroll 1
    for (int c = 0; c < 16; ++c) {
        {
            uint4 sv;
            sv.x = packbf2(xp0.x, xp0.y);
            sv.y = packbf2(xp0.z, xp0.w);
            sv.z = packbf2(xp1.x, xp1.y);
            sv.w = packbf2(xp1.z, xp1.w);
            *(uint4*)&XS[t >> 3][(t & 7) * 8] = sv;
        }
        #pragma unroll
        for (int kt = 0; kt < 2; ++kt) {
            cbq[kt] = pbq[kt]; cbk[kt] = pbk[kt]; cbv[kt] = pbv[kt];
        }
        __syncthreads();

        if (c < 15) {
            const int k0 = (c + 1) * 64;
            xp0 = *(const float4*)(xptr + k0);
            xp1 = *(const float4*)(xptr + k0 + 4);
            #pragma unroll
            for (int kt = 0; kt < 2; ++kt) {
                pbq[kt] = *(const short8*)(wqp + k0 + kt * 32);
                pbk[kt] = *(const short8*)(wkp + k0 + kt * 32);
                pbv[kt] = *(const short8*)(wvp + k0 + kt * 32);
            }
        }

        #pragma unroll
        for (int kt = 0; kt < 2; ++kt) {
            short8 a0 = *(const short8*)&XS[m][kt * 32 + g * 8];
            short8 a1 = *(const short8*)&XS[16 + m][kt * 32 + g * 8];
            accq[0] = __builtin_amdgcn_mfma_f32_16x16x32_bf16(a0, cbq[kt], accq[0], 0, 0, 0);
            accq[1] = __builtin_amdgcn_mfma_f32_16x16x32_bf16(a1, cbq[kt], accq[1], 0, 0, 0);
            acck[0] = __builtin_amdgcn_mfma_f32_16x16x32_bf16(a0, cbk[kt], acck[0], 0, 0, 0);
            acck[1] = __builtin_amdgcn_mfma_f32_16x16x32_bf16(a1, cbk[kt], acck[1], 0, 0, 0);
            accv[0] = __builtin_amdgcn_mfma_f32_16x16x32_bf16(cbv[kt], a0, accv[0], 0, 0, 0);
            accv[1] = __builtin_amdgcn_mfma_f32_16x16x32_bf16(cbv[kt], a1, accv[1], 0, 0, 0);
        }
        __syncthreads();
    }

    const int col   = w * 16 + m;
    const int batch = rb >> 11;
    const int seq0  = rb & (S - 1);
    #pragma unroll
    for (int mt = 0; mt < 2; ++mt) {
        const int orow = rb + mt * 16 + g * 4;
        #pragma unroll
        for (int r = 0; r < 4; ++r) {
            qo[(size_t)(orow + r) * Hd + col] = f2bf(accq[mt][r] * 0.125f);
            ko[(size_t)(orow + r) * Hd + col] = f2bf(acck[mt][r]);
        }
    }
    #pragma unroll
    for (int ns = 0; ns < 2; ++ns)
        #pragma unroll
        for (int r = 0; r < 4; ++r) {
            const int h = w * 16 + g * 4 + r;
            vTo[(size_t)batch * Hd * S + (size_t)h * S + seq0 + ns * 16 + m]
                = f2bf(accv[ns][r]);
        }
}

// ---------------------------------------------------------------------------
// Attention v10 — swapped-operand QK^T (S^T = K·Q^T) makes each lane hold a
// full P-row for ONE q-row (q = m). PV then runs as 4 K-slices of
// mfma_16x16x16: the A-fragment (P[q=m][k=16s+4g+j]) is exactly sacc[s][j],
// LANE-LOCAL — the per-wave PL LDS round-trip (16 scalar ds_write_b16 +
// 2 ds_read_b128 + ~48 VALU of bit-trick converts per wave-iter) is gone.
// l becomes a single per-lane scalar (2-shuffle final reduce).
__global__ __launch_bounds__(256)
void attn_part(const ushort_t* __restrict__ q, const ushort_t* __restrict__ k,
               const ushort_t* __restrict__ vT,
               float* __restrict__ lp, ushort_t* __restrict__ op)
{
    const int bi     = blockIdx.x;
    const int parity = bi & 3;
    const int pr     = bi >> 2;
    const int batch  = pr & 7;
    const int tile   = 31 - (pr >> 3);   // longest-first
    const int qs0    = tile * 64;
    const int sidx   = (batch * 32 + tile) * 4 + parity;

    const ushort_t* kb  = k  + (size_t)batch * S * Hd;
    const ushort_t* vTb = vT + (size_t)batch * Hd * S;

    const int t    = threadIdx.x;
    const int w    = t >> 6;
    const int lane = t & 63;
    const int m    = lane & 15;
    const int g    = lane >> 4;

    __shared__ alignas(16) ushort_t KS [64][LST];
    __shared__ alignas(16) ushort_t VTS[64][LST];

    // Q fragment: lane (m,g) holds Q[q = w*16+m][h = g*8..+8] — serves
    // directly as the B-fragment of the swapped QK MFMA (B[k=h][n=q]).
    const ushort_t* qrow = q + (size_t)(batch * S + qs0 + w * 16 + m) * Hd;
    short8 qf0 = *(const short8*)(qrow + g * 8);
    short8 qf1 = *(const short8*)(qrow + 32 + g * 8);

    f32x4 o[4];
    #pragma unroll
    for (int j = 0; j < 4; ++j) o[j] = (f32x4){0.f, 0.f, 0.f, 0.f};
    float lrun = 0.f;
    const int qr = w * 16 + m;   // q row within the 64-row block (mask)

    const int r1 = t >> 3, c16 = (t & 7) * 8;
    uint4 pk0, pk1, pv0, pv1;

    int c = parity;
    if (c <= tile) {
        const int key0 = c * 64;
        const ushort_t* kt_base = kb + (size_t)key0 * Hd;   // 8 KB flat
        pk0 = *(const uint4*)(kt_base + t * 8);
        pk1 = *(const uint4*)(kt_base + (t + 256) * 8);
        pv0 = *(const uint4*)(vTb + (size_t)r1 * S + key0 + c16);
        pv1 = *(const uint4*)(vTb + (size_t)(r1 + 32) * S + key0 + c16);
    }

    for (; c <= tile; c += 4) {
        *(uint4*)&KS [r1][c16]       = pk0;
        *(uint4*)&KS [r1 + 32][c16]  = pk1;
        *(uint4*)&VTS[r1][c16]       = pv0;
        *(uint4*)&VTS[r1 + 32][c16]  = pv1;
        __syncthreads();

        if (c + 4 <= tile) {
            const int key0n = (c + 4) * 64;
            const ushort_t* kt_base = kb + (size_t)key0n * Hd;
            pk0 = *(const uint4*)(kt_base + t * 8);
            pk1 = *(const uint4*)(kt_base + (t + 256) * 8);
            pv0 = *(const uint4*)(vTb + (size_t)r1 * S + key0n + c16);
            pv1 = *(const uint4*)(vTb + (size_t)(r1 + 32) * S + key0n + c16);
        }

        // ---- S^T = K Q^T (operand-swapped; identical KS reads to before).
        // sacc[nt][r] = S[q = w*16+m][key = nt*16 + g*4 + r]
        f32x4 sacc[4];
        #pragma unroll
        for (int j = 0; j < 4; ++j) sacc[j] = (f32x4){0.f, 0.f, 0.f, 0.f};
        #pragma unroll
        for (int nt = 0; nt < 4; ++nt) {
            short8 b0 = *(const short8*)&KS[nt * 16 + m][g * 8];
            short8 b1 = *(const short8*)&KS[nt * 16 + m][32 + g * 8];
            sacc[nt] = __builtin_amdgcn_mfma_f32_16x16x32_bf16(b0, qf0, sacc[nt], 0, 0, 0);
            sacc[nt] = __builtin_amdgcn_mfma_f32_16x16x32_bf16(b1, qf1, sacc[nt], 0, 0, 0);
        }

        // ---- P = exp(S), causal mask on the diagonal tile (no max shift)
        if (c == tile) {
            #pragma unroll
            for (int nt = 0; nt < 4; ++nt)
                #pragma unroll
                for (int r = 0; r < 4; ++r) {
                    const int keyl = nt * 16 + g * 4 + r;
                    sacc[nt][r] = (keyl > qr) ? 0.f : __expf(sacc[nt][r]);
                }
        } else {
            #pragma unroll
            for (int nt = 0; nt < 4; ++nt)
                #pragma unroll
                for (int r = 0; r < 4; ++r)
                    sacc[nt][r] = __expf(sacc[nt][r]);
        }

        // ---- per-lane l accumulation (single scalar now: q is fixed = m)
        #pragma unroll
        for (int nt = 0; nt < 4; ++nt)
            lrun += (sacc[nt][0] + sacc[nt][1]) + (sacc[nt][2] + sacc[nt][3]);

        // ---- pack P slices to bf16 (pairs -> v_cvt_pk_bf16_f32)
        unsigned pw0[4], pw1[4];
        #pragma unroll
        for (int s = 0; s < 4; ++s) {
            pw0[s] = packbf2(sacc[s][0], sacc[s][1]);
            pw1[s] = packbf2(sacc[s][2], sacc[s][3]);
        }

        // ---- O += P V via 16x16x16 (A-frag is lane-local: no LDS, no shuffle)
        #pragma unroll
        for (int s = 0; s < 4; ++s) {
            short4v pa;
            { unsigned u2[2] = {pw0[s], pw1[s]}; __builtin_memcpy(&pa, u2, 8); }
            #pragma unroll
            for (int nt = 0; nt < 4; ++nt) {
                short4v vb = *(const short4v*)&VTS[nt * 16 + m][s * 16 + g * 4];
                o[nt] = __builtin_amdgcn_mfma_f32_16x16x16bf16_1k(pa, vb, o[nt], 0, 0, 0);
            }
        }
        __syncthreads();
    }

    // ---- final reduce of l across the 4 g-groups (q = m), then write partial
    {
        float ts = lrun;
        ts += __shfl_xor(ts, 16, 64);
        ts += __shfl_xor(ts, 32, 64);
        if (lane < 16) lp[sidx * 64 + w * 16 + m] = ts;
    }
    // O C-layout matches the old one: row q_local = g*4+r, col h = nt*16+m
    #pragma unroll
    for (int nt = 0; nt < 4; ++nt)
        #pragma unroll
        for (int r = 0; r < 4; ++r)
            op[(size_t)sidx * 4096 + (w * 16 + g * 4 + r) * 64 + nt * 16 + m]
                = f2bf(o[nt][r]);
}

// ---------------------------------------------------------------------------
// Attention phase 2: plain sum-merge of 4 parity partials. Grid 256.
__global__ __launch_bounds__(256)
void attn_merge(const float* __restrict__ lp, const ushort_t* __restrict__ op,
                float* __restrict__ out)
{
    const int bq    = blockIdx.x;
    const int batch = bq >> 5;
    const int tile  = bq & 31;
    const int s0    = (batch * 32 + tile) * 4;

    const int t   = threadIdx.x;
    const int row = t >> 2;
    const int c16 = (t & 3) * 16;

    float l = 0.f;
    #pragma unroll
    for (int p = 0; p < 4; ++p) l += lp[(s0 + p) * 64 + row];
    const float inv = 1.f / l;

    float acc[16];
    #pragma unroll
    for (int j = 0; j < 16; ++j) acc[j] = 0.f;
    #pragma unroll
    for (int p = 0; p < 4; ++p) {
        short8 a0 = *(const short8*)(op + (size_t)(s0 + p) * 4096 + row * 64 + c16);
        short8 a1 = *(const short8*)(op + (size_t)(s0 + p) * 4096 + row * 64 + c16 + 8);
        #pragma unroll
        for (int j = 0; j < 8; ++j) {
            acc[j]     += bf2f((ushort_t)a0[j]);
            acc[j + 8] += bf2f((ushort_t)a1[j]);
        }
    }
    float* dst = out + (size_t)(batch * S + tile * 64 + row) * Hd + c16;
    #pragma unroll
    for (int j = 0; j < 16; ++j) dst[j] = acc[j] * inv;
}

// ---------------------------------------------------------------------------
extern "C" void kernel_launch(void* const* d_in, const int* in_sizes, int n_in,
                              void* d_out, int out_size, void* d_ws, size_t ws_size,
                              hipStream_t stream) {
    const float* x  = (const float*)d_in[0];
    const float* Wk = (const float*)d_in[1];
    const float* Wq = (const float*)d_in[2];
    const float* Wv = (const float*)d_in[3];
    float* out = (float*)d_out;

    ushort_t* qws  = (ushort_t*)d_ws;                      // 16384*64 bf16
    ushort_t* kws  = qws + (size_t)ROWS * Hd;
    ushort_t* vTws = kws + (size_t)ROWS * Hd;              // [8][64][2048] bf16
    ushort_t* WT   = vTws + (size_t)ROWS * Hd;             // 192*1024 bf16
    float*    lpp  = (float*)(WT + (size_t)NTOT * E);      // 1024*64 f32
    ushort_t* opp  = (ushort_t*)(lpp + 1024 * 64);         // 1024*4096 bf16

    prep_wt<<<(NTOT * E) / 256, 256, 0, stream>>>(Wk, Wq, Wv, WT);
    proj_v7<<<ROWS / 32, 256, 0, stream>>>(x, WT, qws, kws, vTws);
    attn_part<<<1024, 256, 0, stream>>>(qws, kws, vTws, lpp, opp);
    attn_merge<<<256, 256, 0, stream>>>(lpp, opp, out);
}